// Round 5
// baseline (339.584 us; speedup 1.0000x reference)
//
#include <hip/hip_runtime.h>
#include <math.h>

#define B_ 4
#define N_ 2048
#define DIM_ 3
#define H_ 128
#define K_ 32
#define L_ 4
#define OUT_ 6
#define BN_ (B_*N_)

typedef __attribute__((ext_vector_type(8))) short short8;
typedef __attribute__((ext_vector_type(4))) float f32x4;

#define LDW (H_ + 8)          // padded LDS row (bf16 elems)
#define LAYER_W 98304         // shorts per layer: w1a 16K | w1c 16K | w2 16K | u1 32K | u2 16K
#define OFF_W1A 0
#define OFF_W1C 16384
#define OFF_W2  32768
#define OFF_U1  49152
#define OFF_U2  81920

__device__ __forceinline__ float silu_f(float x) {
    return __fdividef(x, 1.0f + __expf(-x));
}
__device__ __forceinline__ short f2b(float f) {          // fp32 -> bf16 RNE
    unsigned u = __float_as_uint(f);
    return (short)((u + 0x7FFFu + ((u >> 16) & 1u)) >> 16);
}
__device__ __forceinline__ float b2f(short s) {
    return __uint_as_float(((unsigned)(unsigned short)s) << 16);
}
__device__ __forceinline__ unsigned pack2(short lo, short hi) {
    return (unsigned)(unsigned short)lo | ((unsigned)(unsigned short)hi << 16);
}

// ---------------- prep: transpose+cast all layer weights to bf16 [n][k] ----------------
__global__ __launch_bounds__(256) void k_prep(
    const float* __restrict__ miw, const float* __restrict__ mow,
    const float* __restrict__ uiw, const float* __restrict__ uow,
    short* __restrict__ wt)
{
    int gid = blockIdx.x * 256 + threadIdx.x;      // L_*LAYER_W threads exactly
    int l = gid / LAYER_W, o = gid - l * LAYER_W;
    float v;
    if (o < OFF_W1C) {
        int n = o >> 7, k = o & 127;
        v = miw[(size_t)l*257*H_ + k*H_ + n];
    } else if (o < OFF_W2) {
        int oo = o - OFF_W1C, n = oo >> 7, k = oo & 127;
        v = miw[(size_t)l*257*H_ + (128 + k)*H_ + n];
    } else if (o < OFF_U1) {
        int oo = o - OFF_W2, n = oo >> 7, k = oo & 127;
        v = mow[(size_t)l*H_*H_ + k*H_ + n];
    } else if (o < OFF_U2) {
        int oo = o - OFF_U1, n = oo >> 8, k = oo & 255;
        v = uiw[(size_t)l*2*H_*H_ + k*H_ + n];
    } else {
        int oo = o - OFF_U2, n = oo >> 7, k = oo & 127;
        v = uow[(size_t)l*H_*H_ + k*H_ + n];
    }
    wt[gid] = f2b(v);
}

// ---------------- knn: binary-search select of K smallest d^2 per row ----------------
// One wave per row, 4 rows/block. Keys = float bits of d^2 in registers
// (32/lane). NO histogram, NO LDS atomics (R4 post-mortem: concentrated d^2
// exponents made the radix histogram serialize ~10M conflict cycles).
// Wave min/max skips common high bits; then per bit: count keys < Tmid via
// predicated register count + shuffle-sum. Exact K-th key T at the end.
#define KNN_ROWS 4
__global__ __launch_bounds__(256) void k_knn(
    const float* __restrict__ x, int* __restrict__ nidx, float* __restrict__ ndist)
{
    __shared__ float xsx[N_], xsy[N_], xsz[N_];     // SoA: stride-1, conflict-free
    __shared__ int cnt_lt[KNN_ROWS], cnt_eq[KNN_ROWS];
    int b  = blockIdx.x / (N_/KNN_ROWS);
    int i0 = (blockIdx.x % (N_/KNN_ROWS)) * KNN_ROWS;
    const float* xb = x + (size_t)b*N_*3;
    for (int t = threadIdx.x; t < N_*3; t += 256) {
        float v = xb[t];
        int q = t / 3, r = t - q*3;
        float* dst = (r == 0) ? xsx : (r == 1) ? xsy : xsz;
        dst[q] = v;
    }
    __syncthreads();

    int wave = threadIdx.x >> 6, lane = threadIdx.x & 63;
    int i = i0 + wave;
    float xix = xsx[i], xiy = xsy[i], xiz = xsz[i];
    if (lane == 0) { cnt_lt[wave] = 0; cnt_eq[wave] = 0; }

    unsigned u[N_/64];
    unsigned mn = 0xFFFFFFFFu, mx = 0u;
#pragma unroll
    for (int t = 0; t < N_/64; ++t) {
        int j = lane + 64*t;
        float d0 = xix-xsx[j], d1 = xiy-xsy[j], d2 = xiz-xsz[j];
        float d = d0*d0 + d1*d1 + d2*d2;
        unsigned k = __float_as_uint(d);
        if (j == i) k = 0x7F800000u;            // self -> +inf, excluded below
        u[t] = k;
        if (k != 0x7F800000u || j != i) {}      // (no-op, clarity)
        if (j != i) { mn = min(mn, k); mx = max(mx, k); }
    }
    // wave min/max (12 shuffles)
    for (int off = 32; off; off >>= 1) {
        mn = min(mn, (unsigned)__shfl_xor((int)mn, off));
        mx = max(mx, (unsigned)__shfl_xor((int)mx, off));
    }

    unsigned T; int need = K_;
    unsigned diff = mn ^ mx;
    if (diff == 0) {
        T = mn;                                  // all keys equal: all ties
    } else {
        int hb = 31 - __builtin_clz(diff);       // highest differing bit (<=30)
        unsigned lowmask = (hb >= 31) ? 0xFFFFFFFFu : ((2u << hb) - 1u);
        T = mn & ~lowmask;                       // common prefix, low bits 0
        int base = 0;                            // #keys < T
        for (int bit = hb; bit >= 0; --bit) {
            unsigned Tmid = T + (1u << bit);
            int c = 0;
#pragma unroll
            for (int t = 0; t < N_/64; ++t)
                c += (u[t] < Tmid) ? 1 : 0;
            for (int off = 32; off; off >>= 1)
                c += __shfl_xor(c, off);
            int grp = c - base;                  // #keys in [T, Tmid)
            if (need <= grp) {
                // K-th lies in bit=0 subgroup: keep bit 0
            } else {
                need -= grp;
                T = Tmid;
                base = c;
            }
        }
    }
    // T = exact K-th smallest key; take all u<T plus `need` ties (order-free)
    int base_eq = K_ - need;
    size_t rbase = ((size_t)(b*N_ + i)) * K_;
#pragma unroll
    for (int t = 0; t < N_/64; ++t) {
        int pos = -1;
        if (u[t] < T) {
            pos = atomicAdd(&cnt_lt[wave], 1);
        } else if (u[t] == T) {
            int e = atomicAdd(&cnt_eq[wave], 1);
            if (e < need) pos = base_eq + e;
        }
        if (pos >= 0) {
            nidx[rbase + pos]  = lane + 64*t;
            ndist[rbase + pos] = sqrtf(__uint_as_float(u[t]));
        }
    }
}

// ---------------- shared a/c MFMA epilogue: from bf16 h in LDS ----------------
#define MAC 32
__device__ __forceinline__ void ac_mfma_from_lds(
    const short (*h_l)[LDW], int node0, int tid,
    const short* __restrict__ wt1a, const short* __restrict__ wt1c,
    const float* __restrict__ b1,
    short* __restrict__ a, short* __restrict__ c)
{
    int wave = tid >> 6, lane = tid & 63, l15 = lane & 15, quad = lane >> 4;
    f32x4 accA[2][2], accC[2][2];
#pragma unroll
    for (int rt = 0; rt < 2; ++rt)
#pragma unroll
        for (int ct = 0; ct < 2; ++ct) {
            accA[rt][ct] = (f32x4){0.f,0.f,0.f,0.f};
            accC[rt][ct] = (f32x4){0.f,0.f,0.f,0.f};
        }
    int colbase = wave * 32;
#pragma unroll
    for (int kk = 0; kk < 4; ++kk) {
        int k0 = kk*32 + quad*8;
        short8 af0 = *(const short8*)&h_l[l15][k0];
        short8 af1 = *(const short8*)&h_l[16 + l15][k0];
#pragma unroll
        for (int ct = 0; ct < 2; ++ct) {
            int n = colbase + ct*16 + l15;
            short8 bA = *(const short8*)(wt1a + (size_t)n*H_ + k0);
            short8 bC = *(const short8*)(wt1c + (size_t)n*H_ + k0);
            accA[0][ct] = __builtin_amdgcn_mfma_f32_16x16x32_bf16(af0, bA, accA[0][ct], 0, 0, 0);
            accA[1][ct] = __builtin_amdgcn_mfma_f32_16x16x32_bf16(af1, bA, accA[1][ct], 0, 0, 0);
            accC[0][ct] = __builtin_amdgcn_mfma_f32_16x16x32_bf16(af0, bC, accC[0][ct], 0, 0, 0);
            accC[1][ct] = __builtin_amdgcn_mfma_f32_16x16x32_bf16(af1, bC, accC[1][ct], 0, 0, 0);
        }
    }
#pragma unroll
    for (int ct = 0; ct < 2; ++ct) {
        int n = colbase + ct*16 + l15;
        float b1v = b1[n];
#pragma unroll
        for (int rt = 0; rt < 2; ++rt)
#pragma unroll
            for (int r = 0; r < 4; ++r) {
                int m = rt*16 + quad*4 + r;
                size_t gi = (size_t)(node0+m)*H_ + n;
                a[gi] = f2b(accA[rt][ct][r] + b1v);
                c[gi] = f2b(accC[rt][ct][r]);
            }
    }
}

// ---------------- embed + layer-0 a/c ----------------
__global__ __launch_bounds__(256) void k_embed_ac(
    const float* __restrict__ x, const float* __restrict__ ew,
    const float* __restrict__ eb,
    const short* __restrict__ wt1a, const short* __restrict__ wt1c,
    const float* __restrict__ b1,
    float* __restrict__ h, short* __restrict__ a, short* __restrict__ c)
{
    __shared__ __align__(16) short h_l[MAC][LDW];
    int node0 = blockIdx.x * MAC;
    int tid = threadIdx.x;
    for (int t = tid; t < MAC*H_; t += 256) {
        int row = t >> 7, ch = t & 127;
        int gr = node0 + row;
        float v = eb[ch];
        v = fmaf(x[gr*3+0], ew[ch], v);
        v = fmaf(x[gr*3+1], ew[H_+ch], v);
        v = fmaf(x[gr*3+2], ew[2*H_+ch], v);
        h[(size_t)gr*H_ + ch] = v;
        h_l[row][ch] = f2b(v);
    }
    __syncthreads();
    ac_mfma_from_lds(h_l, node0, tid, wt1a, wt1c, b1, a, c);
}

// ---------------- k_edge: s[m][ch] = sum_k silu(a_i + c_j + d*wd)  (bf16 out) ----------------
#define ME 8
__global__ __launch_bounds__(256) void k_edge(
    const unsigned* __restrict__ a2, const unsigned* __restrict__ c2,
    const int* __restrict__ nidx, const float* __restrict__ ndist,
    const float* __restrict__ wd, unsigned* __restrict__ s2)
{
    __shared__ int idx_s[ME][K_];
    __shared__ float dst_s[ME][K_];
    int node0 = blockIdx.x * ME;
    int tid = threadIdx.x;
    for (int t = tid; t < ME*K_; t += 256) {
        idx_s[t>>5][t&31] = nidx[(size_t)node0*K_ + t];
        dst_s[t>>5][t&31] = ndist[(size_t)node0*K_ + t];
    }
    __syncthreads();
    int c2i = tid & 63;
    int grp = tid >> 6;
    int ch0 = c2i * 2;
    float wd0 = wd[ch0], wd1 = wd[ch0+1];
    size_t cbase2 = (size_t)(node0 / N_) * N_ * (H_/2);
#pragma unroll
    for (int mm = 0; mm < 2; ++mm) {
        int m = grp*2 + mm;
        unsigned av = a2[(size_t)(node0+m)*(H_/2) + c2i];
        float a0 = b2f((short)(av & 0xFFFFu)), a1 = b2f((short)(av >> 16));
        float s0 = 0.f, s1 = 0.f;
#pragma unroll 8
        for (int k = 0; k < K_; ++k) {
            int j = idx_s[m][k];
            float dd = dst_s[m][k];
            unsigned cv = c2[cbase2 + (size_t)j*(H_/2) + c2i];
            float cv0 = b2f((short)(cv & 0xFFFFu)), cv1 = b2f((short)(cv >> 16));
            s0 += silu_f(a0 + fmaf(dd, wd0, cv0));
            s1 += silu_f(a1 + fmaf(dd, wd1, cv1));
        }
        s2[(size_t)(node0+m)*(H_/2) + c2i] = pack2(f2b(s0), f2b(s1));
    }
}

// ---------------- k_upd_ac (MFMA x3 + next-layer a/c): ----------------
#define MU 32
__global__ __launch_bounds__(256) void k_upd_ac(
    float* __restrict__ h, const short* __restrict__ s,
    const short* __restrict__ wt2, const float* __restrict__ b2,
    const short* __restrict__ wtu1, const float* __restrict__ u1b,
    const short* __restrict__ wtu2, const float* __restrict__ u2b,
    const short* __restrict__ wn1a, const short* __restrict__ wn1c,
    const float* __restrict__ b1n,
    short* __restrict__ a, short* __restrict__ c)
{
    __shared__ __align__(16) short s_l[MU][LDW];     // s; later reused for t1
    __shared__ __align__(16) short h_l[MU][LDW];     // old h; later new h
    __shared__ __align__(16) short agg_l[MU][LDW];
    int node0 = blockIdx.x * MU;
    int tid = threadIdx.x;
    for (int t = tid; t < MU*H_/4; t += 256) {
        float4 v = reinterpret_cast<const float4*>(h + (size_t)node0*H_)[t];
        int row = t >> 5, col = (t & 31) * 4;
        h_l[row][col+0] = f2b(v.x); h_l[row][col+1] = f2b(v.y);
        h_l[row][col+2] = f2b(v.z); h_l[row][col+3] = f2b(v.w);
    }
    for (int t = tid; t < MU*H_/2; t += 256) {
        unsigned v = reinterpret_cast<const unsigned*>(s + (size_t)node0*H_)[t];
        int row = t >> 6, col = (t & 63) * 2;
        s_l[row][col]   = (short)(v & 0xFFFFu);
        s_l[row][col+1] = (short)(v >> 16);
    }
    __syncthreads();

    int wave = tid >> 6, lane = tid & 63, l15 = lane & 15, quad = lane >> 4;
    int colbase = wave * 32;
    f32x4 acc[2][2];

    // ---- GEMM1: agg = s @ w2 + K*b2 ----
#pragma unroll
    for (int rt = 0; rt < 2; ++rt)
#pragma unroll
        for (int ct = 0; ct < 2; ++ct) acc[rt][ct] = (f32x4){0.f,0.f,0.f,0.f};
#pragma unroll
    for (int kk = 0; kk < 4; ++kk) {
        int k0 = kk*32 + quad*8;
        short8 af0 = *(const short8*)&s_l[l15][k0];
        short8 af1 = *(const short8*)&s_l[16 + l15][k0];
#pragma unroll
        for (int ct = 0; ct < 2; ++ct) {
            int n = colbase + ct*16 + l15;
            short8 bf = *(const short8*)(wt2 + (size_t)n*H_ + k0);
            acc[0][ct] = __builtin_amdgcn_mfma_f32_16x16x32_bf16(af0, bf, acc[0][ct], 0, 0, 0);
            acc[1][ct] = __builtin_amdgcn_mfma_f32_16x16x32_bf16(af1, bf, acc[1][ct], 0, 0, 0);
        }
    }
#pragma unroll
    for (int ct = 0; ct < 2; ++ct) {
        int n = colbase + ct*16 + l15;
        float b2v = b2[n] * (float)K_;
#pragma unroll
        for (int rt = 0; rt < 2; ++rt)
#pragma unroll
            for (int r = 0; r < 4; ++r)
                agg_l[rt*16 + quad*4 + r][n] = f2b(acc[rt][ct][r] + b2v);
    }
    __syncthreads();

    // ---- GEMM2: t1 = silu([h | agg] @ u1 + u1b) -> s_l ----
#pragma unroll
    for (int rt = 0; rt < 2; ++rt)
#pragma unroll
        for (int ct = 0; ct < 2; ++ct) acc[rt][ct] = (f32x4){0.f,0.f,0.f,0.f};
#pragma unroll
    for (int kk = 0; kk < 8; ++kk) {
        const short (*src)[LDW] = (kk < 4) ? h_l : agg_l;
        int kloc = ((kk < 4) ? kk*32 : (kk-4)*32) + quad*8;
        short8 af0 = *(const short8*)&src[l15][kloc];
        short8 af1 = *(const short8*)&src[16 + l15][kloc];
#pragma unroll
        for (int ct = 0; ct < 2; ++ct) {
            int n = colbase + ct*16 + l15;
            short8 bf = *(const short8*)(wtu1 + (size_t)n*2*H_ + kk*32 + quad*8);
            acc[0][ct] = __builtin_amdgcn_mfma_f32_16x16x32_bf16(af0, bf, acc[0][ct], 0, 0, 0);
            acc[1][ct] = __builtin_amdgcn_mfma_f32_16x16x32_bf16(af1, bf, acc[1][ct], 0, 0, 0);
        }
    }
    __syncthreads();     // all reads of h_l/agg_l done
#pragma unroll
    for (int ct = 0; ct < 2; ++ct) {
        int n = colbase + ct*16 + l15;
        float u1bv = u1b[n];
#pragma unroll
        for (int rt = 0; rt < 2; ++rt)
#pragma unroll
            for (int r = 0; r < 4; ++r)
                s_l[rt*16 + quad*4 + r][n] = f2b(silu_f(acc[rt][ct][r] + u1bv));
    }
    __syncthreads();

    // ---- GEMM3: upd = t1 @ u2 + u2b ; h += upd (fp32) ; h_l <- new h (bf16) ----
#pragma unroll
    for (int rt = 0; rt < 2; ++rt)
#pragma unroll
        for (int ct = 0; ct < 2; ++ct) acc[rt][ct] = (f32x4){0.f,0.f,0.f,0.f};
#pragma unroll
    for (int kk = 0; kk < 4; ++kk) {
        int k0 = kk*32 + quad*8;
        short8 af0 = *(const short8*)&s_l[l15][k0];
        short8 af1 = *(const short8*)&s_l[16 + l15][k0];
#pragma unroll
        for (int ct = 0; ct < 2; ++ct) {
            int n = colbase + ct*16 + l15;
            short8 bf = *(const short8*)(wtu2 + (size_t)n*H_ + k0);
            acc[0][ct] = __builtin_amdgcn_mfma_f32_16x16x32_bf16(af0, bf, acc[0][ct], 0, 0, 0);
            acc[1][ct] = __builtin_amdgcn_mfma_f32_16x16x32_bf16(af1, bf, acc[1][ct], 0, 0, 0);
        }
    }
#pragma unroll
    for (int ct = 0; ct < 2; ++ct) {
        int n = colbase + ct*16 + l15;
        float u2bv = u2b[n];
#pragma unroll
        for (int rt = 0; rt < 2; ++rt)
#pragma unroll
            for (int r = 0; r < 4; ++r) {
                int m = rt*16 + quad*4 + r;
                size_t gi = (size_t)(node0+m)*H_ + n;
                float nh = h[gi] + acc[rt][ct][r] + u2bv;
                h[gi] = nh;
                h_l[m][n] = f2b(nh);
            }
    }
    // ---- next layer's a/c from the new h ----
    if (wn1a) {
        __syncthreads();
        ac_mfma_from_lds(h_l, node0, tid, wn1a, wn1c, b1n, a, c);
    }
}

// ---------------- out: out = h @ ow + ob ----------------
__global__ __launch_bounds__(256) void k_out(
    const float* __restrict__ h, const float* __restrict__ ow,
    const float* __restrict__ ob, float* __restrict__ out)
{
    int gid = blockIdx.x * 256 + threadIdx.x;  // BN_*8 threads
    int node = gid >> 3, o = gid & 7;
    if (o < OUT_) {
        float acc = ob[o];
        const float* hrow = h + (size_t)node*H_;
        for (int r = 0; r < H_; ++r)
            acc = fmaf(hrow[r], ow[r*OUT_ + o], acc);
        out[(size_t)node*OUT_ + o] = acc;
    }
}

extern "C" void kernel_launch(void* const* d_in, const int* in_sizes, int n_in,
                              void* d_out, int out_size, void* d_ws, size_t ws_size,
                              hipStream_t stream)
{
    const float* x   = (const float*)d_in[0];
    const float* ew  = (const float*)d_in[1];
    const float* eb  = (const float*)d_in[2];
    const float* miw = (const float*)d_in[3];   // (L,257,H)
    const float* mib = (const float*)d_in[4];   // (L,H)
    const float* mow = (const float*)d_in[5];   // (L,H,H)
    const float* mob = (const float*)d_in[6];   // (L,H)
    const float* uiw = (const float*)d_in[7];   // (L,2H,H)
    const float* uib = (const float*)d_in[8];   // (L,H)
    const float* uow = (const float*)d_in[9];   // (L,H,H)
    const float* uob = (const float*)d_in[10];  // (L,H)
    const float* ow  = (const float*)d_in[11];  // (H,OUT)
    const float* ob  = (const float*)d_in[12];  // (OUT)
    float* out = (float*)d_out;

    // workspace: h fp32 | nd fp32 | ni i32 | a bf16 | c bf16 | s bf16 | wt bf16
    char* w = (char*)d_ws;
    float* h  = (float*)w;                         w += (size_t)BN_*H_*4;
    float* nd = (float*)w;                         w += (size_t)BN_*K_*4;
    int*   ni = (int*)w;                           w += (size_t)BN_*K_*4;
    short* a  = (short*)w;                         w += (size_t)BN_*H_*2;
    short* c  = (short*)w;                         w += (size_t)BN_*H_*2;
    short* s  = (short*)w;                         w += (size_t)BN_*H_*2;
    short* wt = (short*)w;

    k_prep<<<(L_*LAYER_W)/256, 256, 0, stream>>>(miw, mow, uiw, uow, wt);
    k_embed_ac<<<BN_/MAC, 256, 0, stream>>>(x, ew, eb,
        wt + OFF_W1A, wt + OFF_W1C, mib, h, a, c);
    k_knn<<<BN_/KNN_ROWS, 256, 0, stream>>>(x, ni, nd);
    for (int l = 0; l < L_; ++l) {
        const short* wl = wt + (size_t)l*LAYER_W;
        const short* wn = (l+1 < L_) ? wt + (size_t)(l+1)*LAYER_W : nullptr;
        k_edge<<<BN_/ME, 256, 0, stream>>>((const unsigned*)a, (const unsigned*)c,
                                           ni, nd,
                                           miw + (size_t)l*257*H_ + 256*H_,
                                           (unsigned*)s);
        k_upd_ac<<<BN_/MU, 256, 0, stream>>>(h, s,
            wl + OFF_W2, mob + (size_t)l*H_,
            wl + OFF_U1, uib + (size_t)l*H_,
            wl + OFF_U2, uob + (size_t)l*H_,
            wn ? wn + OFF_W1A : nullptr, wn ? wn + OFF_W1C : nullptr,
            wn ? mib + (size_t)(l+1)*H_ : nullptr,
            a, c);
    }
    k_out<<<BN_*8/256, 256, 0, stream>>>(h, ow, ob, out);
}

// Round 6
// 282.642 us; speedup vs baseline: 1.2015x; 1.2015x over previous
//
#include <hip/hip_runtime.h>
#include <math.h>

#define B_ 4
#define N_ 2048
#define DIM_ 3
#define H_ 128
#define K_ 32
#define L_ 4
#define OUT_ 6
#define BN_ (B_*N_)

typedef __attribute__((ext_vector_type(8))) short short8;
typedef __attribute__((ext_vector_type(4))) float f32x4;

#define LDW (H_ + 8)          // padded LDS row (bf16 elems)
#define LAYER_W 98304         // shorts per layer: w1a 16K | w1c 16K | w2 16K | u1 32K | u2 16K
#define OFF_W1A 0
#define OFF_W1C 16384
#define OFF_W2  32768
#define OFF_U1  49152
#define OFF_U2  81920

__device__ __forceinline__ float silu_f(float x) {
    return __fdividef(x, 1.0f + __expf(-x));
}
__device__ __forceinline__ short f2b(float f) {          // fp32 -> bf16 RNE
    unsigned u = __float_as_uint(f);
    return (short)((u + 0x7FFFu + ((u >> 16) & 1u)) >> 16);
}
__device__ __forceinline__ float b2f(short s) {
    return __uint_as_float(((unsigned)(unsigned short)s) << 16);
}
__device__ __forceinline__ unsigned pack2(short lo, short hi) {
    return (unsigned)(unsigned short)lo | ((unsigned)(unsigned short)hi << 16);
}
__device__ __forceinline__ int mbcnt64(unsigned long long m) {   // #set bits below my lane
    return __builtin_amdgcn_mbcnt_hi((unsigned)(m >> 32),
           __builtin_amdgcn_mbcnt_lo((unsigned)m, 0));
}

// ---------------- prep: transpose+cast all layer weights to bf16 [n][k] ----------------
__global__ __launch_bounds__(256) void k_prep(
    const float* __restrict__ miw, const float* __restrict__ mow,
    const float* __restrict__ uiw, const float* __restrict__ uow,
    short* __restrict__ wt)
{
    int gid = blockIdx.x * 256 + threadIdx.x;      // L_*LAYER_W threads exactly
    int l = gid / LAYER_W, o = gid - l * LAYER_W;
    float v;
    if (o < OFF_W1C) {
        int n = o >> 7, k = o & 127;
        v = miw[(size_t)l*257*H_ + k*H_ + n];
    } else if (o < OFF_W2) {
        int oo = o - OFF_W1C, n = oo >> 7, k = oo & 127;
        v = miw[(size_t)l*257*H_ + (128 + k)*H_ + n];
    } else if (o < OFF_U1) {
        int oo = o - OFF_W2, n = oo >> 7, k = oo & 127;
        v = mow[(size_t)l*H_*H_ + k*H_ + n];
    } else if (o < OFF_U2) {
        int oo = o - OFF_U1, n = oo >> 8, k = oo & 255;
        v = uiw[(size_t)l*2*H_*H_ + k*H_ + n];
    } else {
        int oo = o - OFF_U2, n = oo >> 7, k = oo & 127;
        v = uow[(size_t)l*H_*H_ + k*H_ + n];
    }
    wt[gid] = f2b(v);
}

// ---------------- knn: 3-stage ballot select of K smallest d^2 per row ----------------
// R5 post-mortem: counting all 2048 keys per bit-round (31x) was the cost.
// Stage 1: Tup = 32nd smallest of the 64 per-lane minima (upper bound on the
//          global 32nd key: 32 distinct keys are <= it). Counts via ONE
//          ballot + s_bcnt1_b64 per round — no shuffle cascades.
// Stage 2: compact survivors (key <= Tup; expected ~50-100, cap 256,
//          P(overflow) ~ 1e-19 for this data) via ballot-prefix, no atomics.
// Stage 3: exact 32nd among survivors (4 ballots/round), collect via
//          ballot-prefix. Order of output is irrelevant downstream.
#define KNN_ROWS 4
#define SCAP 256
__global__ __launch_bounds__(256) void k_knn(
    const float* __restrict__ x, int* __restrict__ nidx, float* __restrict__ ndist)
{
    __shared__ float xsx[N_], xsy[N_], xsz[N_];          // 24 KB
    __shared__ unsigned skey[KNN_ROWS][SCAP];            // 4 KB
    __shared__ int      sid [KNN_ROWS][SCAP];            // 4 KB
    int b  = blockIdx.x / (N_/KNN_ROWS);
    int i0 = (blockIdx.x % (N_/KNN_ROWS)) * KNN_ROWS;
    const float* xb = x + (size_t)b*N_*3;
    for (int t = threadIdx.x; t < N_*3; t += 256) {
        float v = xb[t];
        int q = t / 3, r = t - q*3;
        float* dst = (r == 0) ? xsx : (r == 1) ? xsy : xsz;
        dst[q] = v;
    }
    __syncthreads();

    int wave = threadIdx.x >> 6, lane = threadIdx.x & 63;
    int i = i0 + wave;
    float xix = xsx[i], xiy = xsy[i], xiz = xsz[i];

    unsigned u[N_/64];
    unsigned lmin = 0xFFFFFFFFu;
#pragma unroll
    for (int t = 0; t < N_/64; ++t) {
        int j = lane + 64*t;
        float d0 = xix-xsx[j], d1 = xiy-xsy[j], d2 = xiz-xsz[j];
        float d = d0*d0 + d1*d1 + d2*d2;
        unsigned k = (j == i) ? 0x7F800000u : __float_as_uint(d);
        u[t] = k;
        lmin = min(lmin, k);
    }

    // Stage 1: Tup = K-th smallest of the 64 lane minima (bitwise, ballot count)
    unsigned Tup = 0;
#pragma unroll
    for (int bit = 30; bit >= 0; --bit) {
        unsigned cand = Tup | (1u << bit);
        unsigned long long m = __ballot(lmin < cand);
        if (__popcll(m) < K_) Tup = cand;
    }

    // Stage 2: compact survivors (key <= Tup) into per-wave LDS, ballot-prefix
    unsigned* sk = skey[wave];
    int*      si = sid [wave];
    int base = 0;
#pragma unroll
    for (int t = 0; t < N_/64; ++t) {
        bool p = (u[t] <= Tup);
        unsigned long long m = __ballot(p);
        if (p) {
            int pos = base + mbcnt64(m);
            if (pos < SCAP) { sk[pos] = u[t]; si[pos] = lane + 64*t; }
        }
        base += __popcll(m);
    }
    int c = min(base, SCAP);

    // Stage 3: exact K-th among survivors (4 slots/lane)
    unsigned sv[4]; int iv[4];
#pragma unroll
    for (int q = 0; q < 4; ++q) {
        int slot = lane + 64*q;
        bool ok = slot < c;
        sv[q] = ok ? sk[slot] : 0xFFFFFFFFu;
        iv[q] = ok ? si[slot] : 0;
    }
    unsigned T = 0;
#pragma unroll
    for (int bit = 30; bit >= 0; --bit) {
        unsigned cand = T | (1u << bit);
        int cnt = __popcll(__ballot(sv[0] < cand)) + __popcll(__ballot(sv[1] < cand))
                + __popcll(__ballot(sv[2] < cand)) + __popcll(__ballot(sv[3] < cand));
        if (cnt < K_) T = cand;
    }
    int cnt_lt = __popcll(__ballot(sv[0] < T)) + __popcll(__ballot(sv[1] < T))
               + __popcll(__ballot(sv[2] < T)) + __popcll(__ballot(sv[3] < T));
    int need = K_ - cnt_lt;          // ties to take (>=1)

    // collect winners: all < T, plus `need` ties == T; positions via ballot-prefix
    size_t rbase = ((size_t)(b*N_ + i)) * K_;
    int ltc = 0, eqc = 0;
#pragma unroll
    for (int q = 0; q < 4; ++q) {
        bool lt = sv[q] < T;
        bool eq = sv[q] == T;
        unsigned long long mlt = __ballot(lt);
        unsigned long long meq = __ballot(eq);
        int p  = ltc + mbcnt64(mlt);
        int e  = eqc + mbcnt64(meq);
        ltc += __popcll(mlt);
        eqc += __popcll(meq);
        int pos = lt ? p : ((eq && e < need) ? (cnt_lt + e) : -1);
        if (pos >= 0) {
            nidx [rbase + pos] = iv[q];
            ndist[rbase + pos] = sqrtf(__uint_as_float(sv[q]));
        }
    }
}

// ---------------- shared a/c MFMA epilogue: 16 rows of bf16 h in LDS ----------------
#define MAC 16
__device__ __forceinline__ void ac_mfma_from_lds(
    const short (*h_l)[LDW], int node0, int tid,
    const short* __restrict__ wt1a, const short* __restrict__ wt1c,
    const float* __restrict__ b1,
    short* __restrict__ a, short* __restrict__ c)
{
    int wave = tid >> 6, lane = tid & 63, l15 = lane & 15, quad = lane >> 4;
    f32x4 accA[2], accC[2];
#pragma unroll
    for (int ct = 0; ct < 2; ++ct) {
        accA[ct] = (f32x4){0.f,0.f,0.f,0.f};
        accC[ct] = (f32x4){0.f,0.f,0.f,0.f};
    }
    int colbase = wave * 32;
#pragma unroll
    for (int kk = 0; kk < 4; ++kk) {
        int k0 = kk*32 + quad*8;
        short8 af = *(const short8*)&h_l[l15][k0];
#pragma unroll
        for (int ct = 0; ct < 2; ++ct) {
            int n = colbase + ct*16 + l15;
            short8 bA = *(const short8*)(wt1a + (size_t)n*H_ + k0);
            short8 bC = *(const short8*)(wt1c + (size_t)n*H_ + k0);
            accA[ct] = __builtin_amdgcn_mfma_f32_16x16x32_bf16(af, bA, accA[ct], 0, 0, 0);
            accC[ct] = __builtin_amdgcn_mfma_f32_16x16x32_bf16(af, bC, accC[ct], 0, 0, 0);
        }
    }
#pragma unroll
    for (int ct = 0; ct < 2; ++ct) {
        int n = colbase + ct*16 + l15;
        float b1v = b1[n];
#pragma unroll
        for (int r = 0; r < 4; ++r) {
            int m = quad*4 + r;
            size_t gi = (size_t)(node0+m)*H_ + n;
            a[gi] = f2b(accA[ct][r] + b1v);
            c[gi] = f2b(accC[ct][r]);
        }
    }
}

// ---------------- embed + layer-0 a/c (grid 512) ----------------
__global__ __launch_bounds__(256) void k_embed_ac(
    const float* __restrict__ x, const float* __restrict__ ew,
    const float* __restrict__ eb,
    const short* __restrict__ wt1a, const short* __restrict__ wt1c,
    const float* __restrict__ b1,
    float* __restrict__ h, short* __restrict__ a, short* __restrict__ c)
{
    __shared__ __align__(16) short h_l[MAC][LDW];
    int node0 = blockIdx.x * MAC;
    int tid = threadIdx.x;
    for (int t = tid; t < MAC*H_; t += 256) {
        int row = t >> 7, ch = t & 127;
        int gr = node0 + row;
        float v = eb[ch];
        v = fmaf(x[gr*3+0], ew[ch], v);
        v = fmaf(x[gr*3+1], ew[H_+ch], v);
        v = fmaf(x[gr*3+2], ew[2*H_+ch], v);
        h[(size_t)gr*H_ + ch] = v;
        h_l[row][ch] = f2b(v);
    }
    __syncthreads();
    ac_mfma_from_lds(h_l, node0, tid, wt1a, wt1c, b1, a, c);
}

// ---------------- k_edge: s[m][ch] = sum_k silu(a_i + c_j + d*wd)  (bf16 out) ----------------
// ME=4: 1 node per wave -> grid 2048 (8 blocks/CU) for gather latency hiding.
#define ME 4
__global__ __launch_bounds__(256) void k_edge(
    const unsigned* __restrict__ a2, const unsigned* __restrict__ c2,
    const int* __restrict__ nidx, const float* __restrict__ ndist,
    const float* __restrict__ wd, unsigned* __restrict__ s2)
{
    __shared__ int idx_s[ME][K_];
    __shared__ float dst_s[ME][K_];
    int node0 = blockIdx.x * ME;
    int tid = threadIdx.x;
    if (tid < ME*K_) {
        idx_s[tid>>5][tid&31] = nidx[(size_t)node0*K_ + tid];
        dst_s[tid>>5][tid&31] = ndist[(size_t)node0*K_ + tid];
    }
    __syncthreads();
    int m   = tid >> 6;                 // node within block
    int c2i = tid & 63;                 // uint index (2 channels)
    int ch0 = c2i * 2;
    float wd0 = wd[ch0], wd1 = wd[ch0+1];
    size_t cbase2 = (size_t)(node0 / N_) * N_ * (H_/2);
    unsigned av = a2[(size_t)(node0+m)*(H_/2) + c2i];
    float a0 = b2f((short)(av & 0xFFFFu)), a1 = b2f((short)(av >> 16));
    float s0 = 0.f, s1 = 0.f;
#pragma unroll 8
    for (int k = 0; k < K_; ++k) {
        int j = idx_s[m][k];
        float dd = dst_s[m][k];
        unsigned cv = c2[cbase2 + (size_t)j*(H_/2) + c2i];
        float cv0 = b2f((short)(cv & 0xFFFFu)), cv1 = b2f((short)(cv >> 16));
        s0 += silu_f(a0 + fmaf(dd, wd0, cv0));
        s1 += silu_f(a1 + fmaf(dd, wd1, cv1));
    }
    s2[(size_t)(node0+m)*(H_/2) + c2i] = pack2(f2b(s0), f2b(s1));
}

// ---------------- k_upd_ac (MFMA x3 + next-layer a/c), 16 nodes/block, grid 512 ----------------
#define MU 16
__global__ __launch_bounds__(256) void k_upd_ac(
    float* __restrict__ h, const short* __restrict__ s,
    const short* __restrict__ wt2, const float* __restrict__ b2,
    const short* __restrict__ wtu1, const float* __restrict__ u1b,
    const short* __restrict__ wtu2, const float* __restrict__ u2b,
    const short* __restrict__ wn1a, const short* __restrict__ wn1c,
    const float* __restrict__ b1n,
    short* __restrict__ a, short* __restrict__ c)
{
    __shared__ __align__(16) short s_l[MU][LDW];     // s; later reused for t1
    __shared__ __align__(16) short h_l[MU][LDW];     // old h; later new h
    __shared__ __align__(16) short agg_l[MU][LDW];
    int node0 = blockIdx.x * MU;
    int tid = threadIdx.x;
    for (int t = tid; t < MU*H_/4; t += 256) {
        float4 v = reinterpret_cast<const float4*>(h + (size_t)node0*H_)[t];
        int row = t >> 5, col = (t & 31) * 4;
        h_l[row][col+0] = f2b(v.x); h_l[row][col+1] = f2b(v.y);
        h_l[row][col+2] = f2b(v.z); h_l[row][col+3] = f2b(v.w);
    }
    for (int t = tid; t < MU*H_/2; t += 256) {
        unsigned v = reinterpret_cast<const unsigned*>(s + (size_t)node0*H_)[t];
        int row = t >> 6, col = (t & 63) * 2;
        s_l[row][col]   = (short)(v & 0xFFFFu);
        s_l[row][col+1] = (short)(v >> 16);
    }
    __syncthreads();

    int wave = tid >> 6, lane = tid & 63, l15 = lane & 15, quad = lane >> 4;
    int colbase = wave * 32;
    f32x4 acc[2];

    // ---- GEMM1: agg = s @ w2 + K*b2 ----
#pragma unroll
    for (int ct = 0; ct < 2; ++ct) acc[ct] = (f32x4){0.f,0.f,0.f,0.f};
#pragma unroll
    for (int kk = 0; kk < 4; ++kk) {
        int k0 = kk*32 + quad*8;
        short8 af = *(const short8*)&s_l[l15][k0];
#pragma unroll
        for (int ct = 0; ct < 2; ++ct) {
            int n = colbase + ct*16 + l15;
            short8 bf = *(const short8*)(wt2 + (size_t)n*H_ + k0);
            acc[ct] = __builtin_amdgcn_mfma_f32_16x16x32_bf16(af, bf, acc[ct], 0, 0, 0);
        }
    }
#pragma unroll
    for (int ct = 0; ct < 2; ++ct) {
        int n = colbase + ct*16 + l15;
        float b2v = b2[n] * (float)K_;
#pragma unroll
        for (int r = 0; r < 4; ++r)
            agg_l[quad*4 + r][n] = f2b(acc[ct][r] + b2v);
    }
    __syncthreads();

    // ---- GEMM2: t1 = silu([h | agg] @ u1 + u1b) -> s_l ----
#pragma unroll
    for (int ct = 0; ct < 2; ++ct) acc[ct] = (f32x4){0.f,0.f,0.f,0.f};
#pragma unroll
    for (int kk = 0; kk < 8; ++kk) {
        const short (*src)[LDW] = (kk < 4) ? h_l : agg_l;
        int kloc = ((kk < 4) ? kk*32 : (kk-4)*32) + quad*8;
        short8 af = *(const short8*)&src[l15][kloc];
#pragma unroll
        for (int ct = 0; ct < 2; ++ct) {
            int n = colbase + ct*16 + l15;
            short8 bf = *(const short8*)(wtu1 + (size_t)n*2*H_ + kk*32 + quad*8);
            acc[ct] = __builtin_amdgcn_mfma_f32_16x16x32_bf16(af, bf, acc[ct], 0, 0, 0);
        }
    }
    __syncthreads();     // all reads of h_l/agg_l/s_l done
#pragma unroll
    for (int ct = 0; ct < 2; ++ct) {
        int n = colbase + ct*16 + l15;
        float u1bv = u1b[n];
#pragma unroll
        for (int r = 0; r < 4; ++r)
            s_l[quad*4 + r][n] = f2b(silu_f(acc[ct][r] + u1bv));
    }
    __syncthreads();

    // ---- GEMM3: upd = t1 @ u2 + u2b ; h += upd (fp32) ; h_l <- new h (bf16) ----
#pragma unroll
    for (int ct = 0; ct < 2; ++ct) acc[ct] = (f32x4){0.f,0.f,0.f,0.f};
#pragma unroll
    for (int kk = 0; kk < 4; ++kk) {
        int k0 = kk*32 + quad*8;
        short8 af = *(const short8*)&s_l[l15][k0];
#pragma unroll
        for (int ct = 0; ct < 2; ++ct) {
            int n = colbase + ct*16 + l15;
            short8 bf = *(const short8*)(wtu2 + (size_t)n*H_ + k0);
            acc[ct] = __builtin_amdgcn_mfma_f32_16x16x32_bf16(af, bf, acc[ct], 0, 0, 0);
        }
    }
#pragma unroll
    for (int ct = 0; ct < 2; ++ct) {
        int n = colbase + ct*16 + l15;
        float u2bv = u2b[n];
#pragma unroll
        for (int r = 0; r < 4; ++r) {
            int m = quad*4 + r;
            size_t gi = (size_t)(node0+m)*H_ + n;
            float nh = h[gi] + acc[ct][r] + u2bv;
            h[gi] = nh;
            h_l[m][n] = f2b(nh);
        }
    }
    // ---- next layer's a/c from the new h ----
    if (wn1a) {
        __syncthreads();
        ac_mfma_from_lds(h_l, node0, tid, wn1a, wn1c, b1n, a, c);
    }
}

// ---------------- out: out = h @ ow + ob ----------------
__global__ __launch_bounds__(256) void k_out(
    const float* __restrict__ h, const float* __restrict__ ow,
    const float* __restrict__ ob, float* __restrict__ out)
{
    int gid = blockIdx.x * 256 + threadIdx.x;  // BN_*8 threads
    int node = gid >> 3, o = gid & 7;
    if (o < OUT_) {
        float acc = ob[o];
        const float* hrow = h + (size_t)node*H_;
        for (int r = 0; r < H_; ++r)
            acc = fmaf(hrow[r], ow[r*OUT_ + o], acc);
        out[(size_t)node*OUT_ + o] = acc;
    }
}

extern "C" void kernel_launch(void* const* d_in, const int* in_sizes, int n_in,
                              void* d_out, int out_size, void* d_ws, size_t ws_size,
                              hipStream_t stream)
{
    const float* x   = (const float*)d_in[0];
    const float* ew  = (const float*)d_in[1];
    const float* eb  = (const float*)d_in[2];
    const float* miw = (const float*)d_in[3];   // (L,257,H)
    const float* mib = (const float*)d_in[4];   // (L,H)
    const float* mow = (const float*)d_in[5];   // (L,H,H)
    const float* mob = (const float*)d_in[6];   // (L,H)
    const float* uiw = (const float*)d_in[7];   // (L,2H,H)
    const float* uib = (const float*)d_in[8];   // (L,H)
    const float* uow = (const float*)d_in[9];   // (L,H,H)
    const float* uob = (const float*)d_in[10];  // (L,H)
    const float* ow  = (const float*)d_in[11];  // (H,OUT)
    const float* ob  = (const float*)d_in[12];  // (OUT)
    float* out = (float*)d_out;

    // workspace: h fp32 | nd fp32 | ni i32 | a bf16 | c bf16 | s bf16 | wt bf16
    char* w = (char*)d_ws;
    float* h  = (float*)w;                         w += (size_t)BN_*H_*4;
    float* nd = (float*)w;                         w += (size_t)BN_*K_*4;
    int*   ni = (int*)w;                           w += (size_t)BN_*K_*4;
    short* a  = (short*)w;                         w += (size_t)BN_*H_*2;
    short* c  = (short*)w;                         w += (size_t)BN_*H_*2;
    short* s  = (short*)w;                         w += (size_t)BN_*H_*2;
    short* wt = (short*)w;

    k_prep<<<(L_*LAYER_W)/256, 256, 0, stream>>>(miw, mow, uiw, uow, wt);
    k_embed_ac<<<BN_/MAC, 256, 0, stream>>>(x, ew, eb,
        wt + OFF_W1A, wt + OFF_W1C, mib, h, a, c);
    k_knn<<<BN_/KNN_ROWS, 256, 0, stream>>>(x, ni, nd);
    for (int l = 0; l < L_; ++l) {
        const short* wl = wt + (size_t)l*LAYER_W;
        const short* wn = (l+1 < L_) ? wt + (size_t)(l+1)*LAYER_W : nullptr;
        k_edge<<<BN_/ME, 256, 0, stream>>>((const unsigned*)a, (const unsigned*)c,
                                           ni, nd,
                                           miw + (size_t)l*257*H_ + 256*H_,
                                           (unsigned*)s);
        k_upd_ac<<<BN_/MU, 256, 0, stream>>>(h, s,
            wl + OFF_W2, mob + (size_t)l*H_,
            wl + OFF_U1, uib + (size_t)l*H_,
            wl + OFF_U2, uob + (size_t)l*H_,
            wn ? wn + OFF_W1A : nullptr, wn ? wn + OFF_W1C : nullptr,
            wn ? mib + (size_t)(l+1)*H_ : nullptr,
            a, c);
    }
    k_out<<<BN_*8/256, 256, 0, stream>>>(h, ow, ob, out);
}